// Round 10
// baseline (293.196 us; speedup 1.0000x reference)
//
#include <hip/hip_runtime.h>
#include <hip/hip_bf16.h>

#define B_ 2
#define S_ 2048
#define E_ 1024
#define H_ 16
#define D_ 64

typedef __bf16 bf16x8 __attribute__((ext_vector_type(8)));
typedef __bf16 bf16x4 __attribute__((ext_vector_type(4)));
typedef float f32x4 __attribute__((ext_vector_type(4)));

// ws layout in bf16 elements:
//   x_bf     : [4096, 1024]        offset 0         (4194304)  <- flash half1 partial O after GEMMs
//   qkvw_bf  : [3072, 1024]        offset 4194304   (3145728)  <- flash l-buffer after GEMMs
//   projw_bf : [1024, 1024]        offset 7340032   (1048576)
//   qk_bf    : [2][B,H,S,D]        offset 8388608   (8388608)
//   vt_bf    : [B,H,D,S]           offset 16777216  (4194304)
//   attn_bf  : [4096, 1024]        offset 20971520  (4194304)  <- flash half0 partial O, merged in place
// total 25165824 elem = 48 MiB

__device__ __forceinline__ f32x4 mfma16(bf16x8 a, bf16x8 b, f32x4 c) {
    return __builtin_amdgcn_mfma_f32_16x16x32_bf16(a, b, c, 0, 0, 0);
}

// async global->LDS, 16B per lane; LDS dest = wave-uniform base + lane*16
__device__ __forceinline__ void gl_lds16(const __bf16* g, __bf16* l) {
    __builtin_amdgcn_global_load_lds(
        (const __attribute__((address_space(1))) unsigned int*)g,
        (__attribute__((address_space(3))) unsigned int*)l, 16, 0, 0);
}

__global__ __launch_bounds__(256) void convert_kernel(
        const float* __restrict__ x, const float* __restrict__ qkvw,
        const float* __restrict__ projw, __bf16* __restrict__ ws) {
    const long NX = 4194304, NW = 3145728;
    long i = (long)(blockIdx.x * 256 + threadIdx.x) * 4;
    const float* src; __bf16* dst; long off;
    if (i < NX)           { src = x;     dst = ws;           off = i; }
    else if (i < NX + NW) { src = qkvw;  dst = ws + NX;      off = i - NX; }
    else                  { src = projw; dst = ws + NX + NW; off = i - NX - NW; }
    float4 v = *(const float4*)(src + off);
    bf16x4 o = { (__bf16)v.x, (__bf16)v.y, (__bf16)v.z, (__bf16)v.w };
    *(bf16x4*)(dst + off) = o;
}

// m97-style GEMM core: 128x128 tile/block (4 waves, 64x64 each), BK=64,
// LDS staging via global_load_lds dwordx4, 2-barrier K-loop.
__device__ __forceinline__ void gemm_core(
        const __bf16* __restrict__ A, const __bf16* __restrict__ Bm,
        int rowT, int colT, int K,
        __bf16* AT, __bf16* BT, f32x4 acc[4][4]) {
    int tid = threadIdx.x;
    int wave = tid >> 6, lane = tid & 63;
    int quad = lane >> 4, lm = lane & 15;
    int wy = wave >> 1, wx = wave & 1;
    int srow = wave * 8 + (lane >> 3);   // + i*32 per staging instr
    int schunk = lane & 7;
    const __bf16* ap = A + (long)(rowT + srow) * K + schunk * 8;
    const __bf16* bp = Bm + (long)(colT + srow) * K + schunk * 8;
    for (int k0 = 0; k0 < K; k0 += 64) {
        __syncthreads();   // previous compute done before LDS overwrite
        for (int i = 0; i < 4; i++) {
            gl_lds16(ap + (long)i * 32 * K + k0, AT + (i * 256 + wave * 64) * 8);
            gl_lds16(bp + (long)i * 32 * K + k0, BT + (i * 256 + wave * 64) * 8);
        }
        __syncthreads();   // vmcnt(0) drain
        for (int ks = 0; ks < 2; ks++) {
            bf16x8 af[4], bfr[4];
            for (int m = 0; m < 4; m++)
                af[m] = *(const bf16x8*)(AT + (wy * 64 + m * 16 + lm) * 64 + ks * 32 + quad * 8);
            for (int n = 0; n < 4; n++)
                bfr[n] = *(const bf16x8*)(BT + (wx * 64 + n * 16 + lm) * 64 + ks * 32 + quad * 8);
            for (int m = 0; m < 4; m++)
                for (int n = 0; n < 4; n++)
                    acc[m][n] = mfma16(af[m], bfr[n], acc[m][n]);
        }
    }
}

#define C1 0.18033688011112043f   // 0.125 * log2(e)

// Q,K: C[t, col] = x @ qkv_w[col,:]^T + b. Q (which==0) is pre-scaled by C1
// so flash's scores come out of the MFMA already in log2 domain.
__global__ __launch_bounds__(256, 2) void qkv_gemm(
        const __bf16* __restrict__ xbf, const __bf16* __restrict__ wbf,
        const float* __restrict__ bias, __bf16* __restrict__ qk) {
    __shared__ __align__(16) __bf16 AT[128 * 64];
    __shared__ __align__(16) __bf16 BT[128 * 64];
    f32x4 acc[4][4] = {};
    int rowT = blockIdx.x * 128, colT = blockIdx.y * 128;
    gemm_core(xbf, wbf, rowT, colT, E_, AT, BT, acc);
    int wave = threadIdx.x >> 6, lane = threadIdx.x & 63;
    int quad = lane >> 4, lm = lane & 15;
    int wy = wave >> 1, wx = wave & 1;
    for (int n = 0; n < 4; n++) {
        int col = colT + wx * 64 + n * 16 + lm;
        float bv = bias[col];
        int which = col >> 10, rem = col & 1023;
        int h = rem >> 6, d = rem & 63;
        float sc = which ? 1.f : C1;
        for (int m = 0; m < 4; m++) {
            int rowb = rowT + wy * 64 + m * 16 + quad * 4;
            for (int r = 0; r < 4; r++) {
                int row = rowb + r;
                int b = row >> 11, s = row & 2047;
                float v = (acc[m][n][r] + bv) * sc;
                qk[(long)((which * B_ + b) * H_ + h) * (S_ * D_) + (long)s * D_ + d] = (__bf16)v;
            }
        }
    }
}

// VT[(b,h,d), t]: A = Wv rows (M=1024), B = x (N=4096 tokens)
__global__ __launch_bounds__(256, 2) void vt_gemm(
        const __bf16* __restrict__ xbf, const __bf16* __restrict__ wvbf,
        const float* __restrict__ bias, __bf16* __restrict__ vt) {
    __shared__ __align__(16) __bf16 AT[128 * 64];
    __shared__ __align__(16) __bf16 BT[128 * 64];
    f32x4 acc[4][4] = {};
    int rowT = blockIdx.x * 128, colT = blockIdx.y * 128;
    gemm_core(wvbf, xbf, rowT, colT, E_, AT, BT, acc);
    int wave = threadIdx.x >> 6, lane = threadIdx.x & 63;
    int quad = lane >> 4, lm = lane & 15;
    int wy = wave >> 1, wx = wave & 1;
    for (int n = 0; n < 4; n++) {
        int t = colT + wx * 64 + n * 16 + lm;
        int b = t >> 11, s = t & 2047;
        for (int m = 0; m < 4; m++) {
            int rowb = rowT + wy * 64 + m * 16 + quad * 4;
            for (int r = 0; r < 4; r++) {
                int mr = rowb + r;          // v-row: h*64+d
                int h = mr >> 6, d = mr & 63;
                float v = acc[m][n][r] + bias[2048 + mr];
                vt[(long)((b * H_ + h) * D_ + d) * S_ + s] = (__bf16)v;
            }
        }
    }
}

// r10: r9's fixed-max short chain + K-split x2 (blockIdx.z) -> 1024 blocks =
// 4/CU = 4 waves/SIMD. r8's split failed on the OLD chain (shuffle/rescale
// latency, TLP-insensitive); r9's chain is issue-dominated (VALUBusy 32% at
// 2 waves/SIMD) so doubling resident waves should convert idle slots into
// exp2/VALU issue. Fixed max M=32 makes the merge trivial: both halves share
// the same shift -> O = (O0+O1)/(l0+l1), unnormalized bf16 partials + float l
// per (half,bh,s). No (m,alpha) bookkeeping anywhere.
__global__ __launch_bounds__(256, 4) void flash_attn(
        const __bf16* __restrict__ qk, const __bf16* __restrict__ vt,
        const int* __restrict__ mask, __bf16* __restrict__ dst0,
        __bf16* __restrict__ dst1, float* __restrict__ lbuf) {
    int wave = threadIdx.x >> 6, lane = threadIdx.x & 63;
    int quad = lane >> 4, lm = lane & 15;
    int bh = blockIdx.x;      // 0..31  (XCD = bh % 8)
    int qt = blockIdx.y;      // 0..15
    int half = blockIdx.z;    // 0..1
    int koff = half << 10;
    int b = bh >> 4, h = bh & 15;
    const long BHSD = (long)B_ * H_ * S_ * D_;
    const __bf16* qp  = qk + (long)bh * (S_ * D_);
    const __bf16* kp  = qk + BHSD + (long)bh * (S_ * D_);
    const __bf16* vtp = vt + (long)bh * (D_ * S_);   // [d][s]
    const int* mrow = mask + b * S_;

    int q0[2];
    q0[0] = qt * 128 + wave * 16;
    q0[1] = q0[0] + 64;
    bf16x8 qa[2][2];
    for (int t = 0; t < 2; t++)
        for (int x = 0; x < 2; x++)
            qa[t][x] = *(const bf16x8*)(qp + (long)(q0[t] + lm) * D_ + x * 32 + quad * 8);

    f32x4 O[2][4] = {};
    float lsum[2] = {0.f, 0.f};

    __shared__ __bf16 Plds[4][2][16][72];   // stride 72: 64 keys + 8 pad

    for (int kb = koff; kb < koff + 1024; kb += 64) {
        bf16x8 kf[4][2];
        int4 mq[4];
        for (int hh = 0; hh < 4; hh++) {
            const __bf16* krow = kp + (long)(kb + hh * 16 + lm) * D_ + quad * 8;
            kf[hh][0] = *(const bf16x8*)(krow);
            kf[hh][1] = *(const bf16x8*)(krow + 32);
            mq[hh] = *(const int4*)(mrow + kb + hh * 16 + quad * 4);
        }
        bf16x8 vf[4][2];
        for (int c = 0; c < 4; c++) {
            const __bf16* vrow = vtp + (long)(c * 16 + lm) * S_ + kb + quad * 8;
            vf[c][0] = *(const bf16x8*)(vrow);
            vf[c][1] = *(const bf16x8*)(vrow + 32);
        }
        // S^T[key][q]: row = quad*4+r = local key, col = lm = local q
        f32x4 st[2][4];
        for (int hh = 0; hh < 4; hh++)
            for (int t = 0; t < 2; t++) {
                f32x4 z = {};
                z = mfma16(kf[hh][0], qa[t][0], z);
                st[t][hh] = mfma16(kf[hh][1], qa[t][1], z);
            }
        // p = exp2(s - 32); masked -> exp2(-1e38) underflows to 0.
        for (int t = 0; t < 2; t++)
            for (int hh = 0; hh < 4; hh++) {
                int mr[4] = {mq[hh].x, mq[hh].y, mq[hh].z, mq[hh].w};
                float e0 = exp2f(mr[0] ? st[t][hh][0] - 32.f : -1e38f);
                float e1 = exp2f(mr[1] ? st[t][hh][1] - 32.f : -1e38f);
                float e2 = exp2f(mr[2] ? st[t][hh][2] - 32.f : -1e38f);
                float e3 = exp2f(mr[3] ? st[t][hh][3] - 32.f : -1e38f);
                lsum[t] += (e0 + e1) + (e2 + e3);
                bf16x4 pk = { (__bf16)e0, (__bf16)e1, (__bf16)e2, (__bf16)e3 };
                *(bf16x4*)(&Plds[wave][t][lm][hh * 16 + quad * 4]) = pk;
            }
        for (int t = 0; t < 2; t++) {
            bf16x8 pa0 = *(const bf16x8*)(&Plds[wave][t][lm][quad * 8]);
            bf16x8 pa1 = *(const bf16x8*)(&Plds[wave][t][lm][32 + quad * 8]);
            for (int c = 0; c < 4; c++) {
                O[t][c] = mfma16(pa0, vf[c][0], O[t][c]);
                O[t][c] = mfma16(pa1, vf[c][1], O[t][c]);
            }
        }
    }
    // one cross-lane l reduction for the whole kernel
    for (int t = 0; t < 2; t++) {
        lsum[t] += __shfl_xor(lsum[t], 16);
        lsum[t] += __shfl_xor(lsum[t], 32);
    }
    __bf16* dst = half ? dst1 : dst0;
    for (int t = 0; t < 2; t++) {
        for (int r = 0; r < 4; r++) {
            int s = q0[t] + quad * 4 + r;
            for (int c = 0; c < 4; c++) {
                int e = h * 64 + c * 16 + lm;
                dst[(long)(b * S_ + s) * E_ + e] = (__bf16)O[t][c][r];  // unnormalized
            }
        }
        if (quad == 0) {
            int s = q0[t] + lm;
            lbuf[((half * 32 + bh) << 11) + s] = lsum[t];
        }
    }
}

// Combine halves: O = (O0 + O1) / (l0 + l1). In-place into o0 (attn_bf).
__global__ __launch_bounds__(256) void merge_kernel(
        __bf16* __restrict__ o0, const __bf16* __restrict__ o1,
        const float* __restrict__ lbuf) {
    int row = blockIdx.x;            // 0..4095 = b*2048+s
    int col = threadIdx.x * 4;       // 0..1023
    int b = row >> 11, s = row & 2047;
    int h = col >> 6;
    int bh = b * 16 + h;
    float l0 = lbuf[(bh << 11) + s];
    float l1 = lbuf[((32 + bh) << 11) + s];
    float d = l0 + l1;
    float inv = d > 0.f ? 1.f / d : 0.f;
    long idx = (long)row * E_ + col;
    bf16x4 a = *(const bf16x4*)(o0 + idx);
    bf16x4 c = *(const bf16x4*)(o1 + idx);
    bf16x4 o;
    for (int i = 0; i < 4; i++)
        o[i] = (__bf16)(((float)a[i] + (float)c[i]) * inv);
    *(bf16x4*)(o0 + idx) = o;
}

// out[M,N] = A[M,K] @ W[N,K]^T + bias, fp32 out
__global__ __launch_bounds__(256, 2) void proj_gemm(
        const __bf16* __restrict__ abf, const __bf16* __restrict__ wbf,
        const float* __restrict__ bias, float* __restrict__ out) {
    __shared__ __align__(16) __bf16 AT[128 * 64];
    __shared__ __align__(16) __bf16 BT[128 * 64];
    f32x4 acc[4][4] = {};
    int rowT = blockIdx.x * 128, colT = blockIdx.y * 128;
    gemm_core(abf, wbf, rowT, colT, E_, AT, BT, acc);
    int wave = threadIdx.x >> 6, lane = threadIdx.x & 63;
    int quad = lane >> 4, lm = lane & 15;
    int wy = wave >> 1, wx = wave & 1;
    for (int n = 0; n < 4; n++) {
        int col = colT + wx * 64 + n * 16 + lm;
        float bv = bias[col];
        for (int m = 0; m < 4; m++) {
            int rowb = rowT + wy * 64 + m * 16 + quad * 4;
            for (int r = 0; r < 4; r++) {
                int row = rowb + r;
                out[(long)row * E_ + col] = acc[m][n][r] + bv;
            }
        }
    }
}

extern "C" void kernel_launch(void* const* d_in, const int* in_sizes, int n_in,
                              void* d_out, int out_size, void* d_ws, size_t ws_size,
                              hipStream_t stream) {
    const float* x      = (const float*)d_in[0];
    const int*   mask   = (const int*)d_in[1];
    const float* qkv_w  = (const float*)d_in[2];
    const float* qkv_b  = (const float*)d_in[3];
    const float* proj_w = (const float*)d_in[4];
    const float* proj_b = (const float*)d_in[5];
    float* out = (float*)d_out;
    __bf16* ws = (__bf16*)d_ws;

    __bf16* x_bf     = ws;                    // also: flash half1 partial O
    __bf16* qkvw_bf  = ws + 4194304;          // also: flash l-buffer
    __bf16* projw_bf = ws + 7340032;
    __bf16* qk_bf    = ws + 8388608;
    __bf16* vt_bf    = ws + 16777216;
    __bf16* attn_bf  = ws + 20971520;         // flash half0 partial O -> merged

    convert_kernel<<<8192, 256, 0, stream>>>(x, qkv_w, proj_w, ws);
    qkv_gemm<<<dim3(32, 16), 256, 0, stream>>>(x_bf, qkvw_bf, qkv_b, qk_bf);
    vt_gemm<<<dim3(8, 32), 256, 0, stream>>>(x_bf, qkvw_bf + 2 * E_ * E_, qkv_b, vt_bf);
    // x_bf / qkvw_bf dead from here -> flash partial buffers
    flash_attn<<<dim3(32, 16, 2), 256, 0, stream>>>(
        qk_bf, vt_bf, mask, attn_bf, x_bf, (float*)qkvw_bf);
    merge_kernel<<<4096, 256, 0, stream>>>(attn_bf, x_bf, (const float*)qkvw_bf);
    proj_gemm<<<dim3(32, 8), 256, 0, stream>>>(attn_bf, projw_bf, proj_b, out);
}

// Round 11
// 279.276 us; speedup vs baseline: 1.0498x; 1.0498x over previous
//
#include <hip/hip_runtime.h>
#include <hip/hip_bf16.h>

#define B_ 2
#define S_ 2048
#define E_ 1024
#define H_ 16
#define D_ 64

typedef __bf16 bf16x8 __attribute__((ext_vector_type(8)));
typedef __bf16 bf16x4 __attribute__((ext_vector_type(4)));
typedef float f32x4 __attribute__((ext_vector_type(4)));

// ws layout in bf16 elements:
//   x_bf     : [4096, 1024]        offset 0         (4194304)
//   qkvw_bf  : [3072, 1024]        offset 4194304   (3145728)
//   projw_bf : [1024, 1024]        offset 7340032   (1048576)
//   qk_bf    : [2][B,H,S,D]        offset 8388608   (8388608)
//   vt_bf    : [B,H,D,S]           offset 16777216  (4194304)
//   attn_bf  : [4096, 1024]        offset 20971520  (4194304)
// total 25165824 elem = 48 MiB

__device__ __forceinline__ f32x4 mfma16(bf16x8 a, bf16x8 b, f32x4 c) {
    return __builtin_amdgcn_mfma_f32_16x16x32_bf16(a, b, c, 0, 0, 0);
}

// async global->LDS, 16B per lane; LDS dest = wave-uniform base + lane*16
__device__ __forceinline__ void gl_lds16(const __bf16* g, __bf16* l) {
    __builtin_amdgcn_global_load_lds(
        (const __attribute__((address_space(1))) unsigned int*)g,
        (__attribute__((address_space(3))) unsigned int*)l, 16, 0, 0);
}

__global__ __launch_bounds__(256) void convert_kernel(
        const float* __restrict__ x, const float* __restrict__ qkvw,
        const float* __restrict__ projw, __bf16* __restrict__ ws) {
    const long NX = 4194304, NW = 3145728;
    long i = (long)(blockIdx.x * 256 + threadIdx.x) * 4;
    const float* src; __bf16* dst; long off;
    if (i < NX)           { src = x;     dst = ws;           off = i; }
    else if (i < NX + NW) { src = qkvw;  dst = ws + NX;      off = i - NX; }
    else                  { src = projw; dst = ws + NX + NW; off = i - NX - NW; }
    float4 v = *(const float4*)(src + off);
    bf16x4 o = { (__bf16)v.x, (__bf16)v.y, (__bf16)v.z, (__bf16)v.w };
    *(bf16x4*)(dst + off) = o;
}

// m97-style GEMM core: 128x128 tile/block (4 waves, 64x64 each), BK=64.
__device__ __forceinline__ void gemm_core(
        const __bf16* __restrict__ A, const __bf16* __restrict__ Bm,
        int rowT, int colT, int K,
        __bf16* AT, __bf16* BT, f32x4 acc[4][4]) {
    int tid = threadIdx.x;
    int wave = tid >> 6, lane = tid & 63;
    int quad = lane >> 4, lm = lane & 15;
    int wy = wave >> 1, wx = wave & 1;
    int srow = wave * 8 + (lane >> 3);
    int schunk = lane & 7;
    const __bf16* ap = A + (long)(rowT + srow) * K + schunk * 8;
    const __bf16* bp = Bm + (long)(colT + srow) * K + schunk * 8;
    for (int k0 = 0; k0 < K; k0 += 64) {
        __syncthreads();
        for (int i = 0; i < 4; i++) {
            gl_lds16(ap + (long)i * 32 * K + k0, AT + (i * 256 + wave * 64) * 8);
            gl_lds16(bp + (long)i * 32 * K + k0, BT + (i * 256 + wave * 64) * 8);
        }
        __syncthreads();
        for (int ks = 0; ks < 2; ks++) {
            bf16x8 af[4], bfr[4];
            for (int m = 0; m < 4; m++)
                af[m] = *(const bf16x8*)(AT + (wy * 64 + m * 16 + lm) * 64 + ks * 32 + quad * 8);
            for (int n = 0; n < 4; n++)
                bfr[n] = *(const bf16x8*)(BT + (wx * 64 + n * 16 + lm) * 64 + ks * 32 + quad * 8);
            for (int m = 0; m < 4; m++)
                for (int n = 0; n < 4; n++)
                    acc[m][n] = mfma16(af[m], bfr[n], acc[m][n]);
        }
    }
}

// 128x64 variant: 4 waves of 32x64 each -> half the block work, 2x the blocks.
// r11: vt/proj were 256 blocks = 1 block/CU (half the machine idle).
__device__ __forceinline__ void gemm_core_h(
        const __bf16* __restrict__ A, const __bf16* __restrict__ Bm,
        int rowT, int colT, int K,
        __bf16* AT, __bf16* BT, f32x4 acc[2][4]) {
    int tid = threadIdx.x;
    int wave = tid >> 6, lane = tid & 63;
    int quad = lane >> 4, lm = lane & 15;
    int srow = wave * 8 + (lane >> 3);
    int schunk = lane & 7;
    const __bf16* ap = A + (long)(rowT + srow) * K + schunk * 8;
    const __bf16* bp = Bm + (long)(colT + srow) * K + schunk * 8;
    for (int k0 = 0; k0 < K; k0 += 64) {
        __syncthreads();
        for (int i = 0; i < 4; i++)
            gl_lds16(ap + (long)i * 32 * K + k0, AT + (i * 256 + wave * 64) * 8);
        for (int i = 0; i < 2; i++)
            gl_lds16(bp + (long)i * 32 * K + k0, BT + (i * 256 + wave * 64) * 8);
        __syncthreads();
        for (int ks = 0; ks < 2; ks++) {
            bf16x8 af[2], bfr[4];
            for (int m = 0; m < 2; m++)
                af[m] = *(const bf16x8*)(AT + (wave * 32 + m * 16 + lm) * 64 + ks * 32 + quad * 8);
            for (int n = 0; n < 4; n++)
                bfr[n] = *(const bf16x8*)(BT + (n * 16 + lm) * 64 + ks * 32 + quad * 8);
            for (int m = 0; m < 2; m++)
                for (int n = 0; n < 4; n++)
                    acc[m][n] = mfma16(af[m], bfr[n], acc[m][n]);
        }
    }
}

#define C1 0.18033688011112043f   // 0.125 * log2(e)

// Q,K: C[t, col] = x @ qkv_w[col,:]^T + b. Q pre-scaled by C1 (log2 domain).
__global__ __launch_bounds__(256, 2) void qkv_gemm(
        const __bf16* __restrict__ xbf, const __bf16* __restrict__ wbf,
        const float* __restrict__ bias, __bf16* __restrict__ qk) {
    __shared__ __align__(16) __bf16 AT[128 * 64];
    __shared__ __align__(16) __bf16 BT[128 * 64];
    f32x4 acc[4][4] = {};
    int rowT = blockIdx.x * 128, colT = blockIdx.y * 128;
    gemm_core(xbf, wbf, rowT, colT, E_, AT, BT, acc);
    int wave = threadIdx.x >> 6, lane = threadIdx.x & 63;
    int quad = lane >> 4, lm = lane & 15;
    int wy = wave >> 1, wx = wave & 1;
    for (int n = 0; n < 4; n++) {
        int col = colT + wx * 64 + n * 16 + lm;
        float bv = bias[col];
        int which = col >> 10, rem = col & 1023;
        int h = rem >> 6, d = rem & 63;
        float sc = which ? 1.f : C1;
        for (int m = 0; m < 4; m++) {
            int rowb = rowT + wy * 64 + m * 16 + quad * 4;
            for (int r = 0; r < 4; r++) {
                int row = rowb + r;
                int b = row >> 11, s = row & 2047;
                float v = (acc[m][n][r] + bv) * sc;
                qk[(long)((which * B_ + b) * H_ + h) * (S_ * D_) + (long)s * D_ + d] = (__bf16)v;
            }
        }
    }
}

// VT[(b,h,d), t]: A = Wv rows (M=1024), B = x (N=4096 tokens); 128x64 tiles.
__global__ __launch_bounds__(256, 2) void vt_gemm(
        const __bf16* __restrict__ xbf, const __bf16* __restrict__ wvbf,
        const float* __restrict__ bias, __bf16* __restrict__ vt) {
    __shared__ __align__(16) __bf16 AT[128 * 64];
    __shared__ __align__(16) __bf16 BT[64 * 64];
    f32x4 acc[2][4] = {};
    int rowT = blockIdx.x * 128, colT = blockIdx.y * 64;
    gemm_core_h(wvbf, xbf, rowT, colT, E_, AT, BT, acc);
    int wave = threadIdx.x >> 6, lane = threadIdx.x & 63;
    int quad = lane >> 4, lm = lane & 15;
    for (int n = 0; n < 4; n++) {
        int t = colT + n * 16 + lm;
        int b = t >> 11, s = t & 2047;
        for (int m = 0; m < 2; m++) {
            int rowb = rowT + wave * 32 + m * 16 + quad * 4;
            for (int r = 0; r < 4; r++) {
                int mr = rowb + r;          // v-row: h*64+d
                int h = mr >> 6, d = mr & 63;
                float v = acc[m][n][r] + bias[2048 + mr];
                vt[(long)((b * H_ + h) * D_ + d) * S_ + s] = (__bf16)v;
            }
        }
    }
}

// ---- flash helpers: load a 64-key K/V/mask tile into registers ----
struct KVTile { bf16x8 kf[4][2]; bf16x8 vf[4][2]; int4 mq[4]; };

__device__ __forceinline__ void load_kv(
        int kb, const __bf16* kp, const __bf16* vtp, const int* mrow,
        int quad, int lm, KVTile& T) {
    for (int hh = 0; hh < 4; hh++) {
        const __bf16* krow = kp + (long)(kb + hh * 16 + lm) * D_ + quad * 8;
        T.kf[hh][0] = *(const bf16x8*)(krow);
        T.kf[hh][1] = *(const bf16x8*)(krow + 32);
        T.mq[hh] = *(const int4*)(mrow + kb + hh * 16 + quad * 4);
    }
    for (int c = 0; c < 4; c++) {
        const __bf16* vrow = vtp + (long)(c * 16 + lm) * S_ + kb + quad * 8;
        T.vf[c][0] = *(const bf16x8*)(vrow);
        T.vf[c][1] = *(const bf16x8*)(vrow + 32);
    }
}

// one 64-key iteration: QK with cur, prefetch next, softmax, PV with cur
__device__ __forceinline__ void flash_iter(
        int nkb, const __bf16* kp, const __bf16* vtp, const int* mrow,
        KVTile& cur, KVTile& nxt, const bf16x8 (&qa)[2][2],
        f32x4 (&O)[2][4], float (&lsum)[2],
        __bf16 (&P)[2][16][72], int quad, int lm) {
    // QK^T (cur.kf was loaded >= one full iteration ago)
    f32x4 st[2][4];
    for (int hh = 0; hh < 4; hh++)
        for (int t = 0; t < 2; t++) {
            f32x4 z = {};
            z = mfma16(cur.kf[hh][0], qa[t][0], z);
            st[t][hh] = mfma16(cur.kf[hh][1], qa[t][1], z);
        }
    // prefetch next tile — ~full iteration of slack before its use
    load_kv(nkb, kp, vtp, mrow, quad, lm, nxt);
    // p = exp2(s - 32); masked -> underflow to 0 (fixed-max softmax)
    for (int t = 0; t < 2; t++)
        for (int hh = 0; hh < 4; hh++) {
            int mr[4] = {cur.mq[hh].x, cur.mq[hh].y, cur.mq[hh].z, cur.mq[hh].w};
            float e0 = exp2f(mr[0] ? st[t][hh][0] - 32.f : -1e38f);
            float e1 = exp2f(mr[1] ? st[t][hh][1] - 32.f : -1e38f);
            float e2 = exp2f(mr[2] ? st[t][hh][2] - 32.f : -1e38f);
            float e3 = exp2f(mr[3] ? st[t][hh][3] - 32.f : -1e38f);
            lsum[t] += (e0 + e1) + (e2 + e3);
            bf16x4 pk = { (__bf16)e0, (__bf16)e1, (__bf16)e2, (__bf16)e3 };
            *(bf16x4*)(&P[t][lm][hh * 16 + quad * 4]) = pk;
        }
    for (int t = 0; t < 2; t++) {
        bf16x8 pa0 = *(const bf16x8*)(&P[t][lm][quad * 8]);
        bf16x8 pa1 = *(const bf16x8*)(&P[t][lm][32 + quad * 8]);
        for (int c = 0; c < 4; c++) {
            O[t][c] = mfma16(pa0, cur.vf[c][0], O[t][c]);
            O[t][c] = mfma16(pa1, cur.vf[c][1], O[t][c]);
        }
    }
}

// r11: r9 structure (no K-split — r8/r10 proved split neutral-negative) +
// register double-buffered K/V/mask prefetch. r10's occupancy-invariance
// says the wall is a fixed per-iter latency segment; the K/V L2 load wait
// (loads issued immediately before QK use) is the prime suspect. Prefetch
// moves next tile's loads ~1500 cyc ahead of use.
__global__ __launch_bounds__(256, 2) void flash_attn(
        const __bf16* __restrict__ qk, const __bf16* __restrict__ vt,
        const int* __restrict__ mask, __bf16* __restrict__ attn) {
    int wave = threadIdx.x >> 6, lane = threadIdx.x & 63;
    int quad = lane >> 4, lm = lane & 15;
    int bh = blockIdx.x;      // 0..31  (XCD = bh % 8)
    int qt = blockIdx.y;      // 0..15
    int b = bh >> 4, h = bh & 15;
    const long BHSD = (long)B_ * H_ * S_ * D_;
    const __bf16* qp  = qk + (long)bh * (S_ * D_);
    const __bf16* kp  = qk + BHSD + (long)bh * (S_ * D_);
    const __bf16* vtp = vt + (long)bh * (D_ * S_);   // [d][s]
    const int* mrow = mask + b * S_;

    int q0[2];
    q0[0] = qt * 128 + wave * 16;
    q0[1] = q0[0] + 64;
    bf16x8 qa[2][2];
    for (int t = 0; t < 2; t++)
        for (int x = 0; x < 2; x++)
            qa[t][x] = *(const bf16x8*)(qp + (long)(q0[t] + lm) * D_ + x * 32 + quad * 8);

    f32x4 O[2][4] = {};
    float lsum[2] = {0.f, 0.f};

    __shared__ __bf16 Plds[4][2][16][72];

    KVTile TA, TB;
    load_kv(0, kp, vtp, mrow, quad, lm, TA);
    for (int kb = 0; kb < S_; kb += 128) {
        flash_iter(kb + 64, kp, vtp, mrow, TA, TB, qa, O, lsum,
                   Plds[wave], quad, lm);
        int nn = (kb + 128) & (S_ - 1);   // wraps to 0 on last (redundant load)
        flash_iter(nn, kp, vtp, mrow, TB, TA, qa, O, lsum,
                   Plds[wave], quad, lm);
    }
    for (int t = 0; t < 2; t++) {
        lsum[t] += __shfl_xor(lsum[t], 16);
        lsum[t] += __shfl_xor(lsum[t], 32);
    }
    for (int t = 0; t < 2; t++)
        for (int r = 0; r < 4; r++) {
            float lb = __shfl(lsum[t], quad * 4 + r);
            float inv = lb > 0.f ? 1.f / lb : 0.f;
            int s = q0[t] + quad * 4 + r;
            for (int c = 0; c < 4; c++) {
                int e = h * 64 + c * 16 + lm;
                attn[(long)(b * S_ + s) * E_ + e] = (__bf16)(O[t][c][r] * inv);
            }
        }
}

// out[M,N] = A[M,K] @ W[N,K]^T + bias, fp32 out; 128x64 tiles.
__global__ __launch_bounds__(256, 2) void proj_gemm(
        const __bf16* __restrict__ abf, const __bf16* __restrict__ wbf,
        const float* __restrict__ bias, float* __restrict__ out) {
    __shared__ __align__(16) __bf16 AT[128 * 64];
    __shared__ __align__(16) __bf16 BT[64 * 64];
    f32x4 acc[2][4] = {};
    int rowT = blockIdx.x * 128, colT = blockIdx.y * 64;
    gemm_core_h(abf, wbf, rowT, colT, E_, AT, BT, acc);
    int wave = threadIdx.x >> 6, lane = threadIdx.x & 63;
    int quad = lane >> 4, lm = lane & 15;
    for (int n = 0; n < 4; n++) {
        int col = colT + n * 16 + lm;
        float bv = bias[col];
        for (int m = 0; m < 2; m++) {
            int rowb = rowT + wave * 32 + m * 16 + quad * 4;
            for (int r = 0; r < 4; r++) {
                int row = rowb + r;
                out[(long)row * E_ + col] = acc[m][n][r] + bv;
            }
        }
    }
}

extern "C" void kernel_launch(void* const* d_in, const int* in_sizes, int n_in,
                              void* d_out, int out_size, void* d_ws, size_t ws_size,
                              hipStream_t stream) {
    const float* x      = (const float*)d_in[0];
    const int*   mask   = (const int*)d_in[1];
    const float* qkv_w  = (const float*)d_in[2];
    const float* qkv_b  = (const float*)d_in[3];
    const float* proj_w = (const float*)d_in[4];
    const float* proj_b = (const float*)d_in[5];
    float* out = (float*)d_out;
    __bf16* ws = (__bf16*)d_ws;

    __bf16* x_bf     = ws;
    __bf16* qkvw_bf  = ws + 4194304;
    __bf16* projw_bf = ws + 7340032;
    __bf16* qk_bf    = ws + 8388608;
    __bf16* vt_bf    = ws + 16777216;
    __bf16* attn_bf  = ws + 20971520;

    convert_kernel<<<8192, 256, 0, stream>>>(x, qkv_w, proj_w, ws);
    qkv_gemm<<<dim3(32, 16), 256, 0, stream>>>(x_bf, qkvw_bf, qkv_b, qk_bf);
    vt_gemm<<<dim3(8, 64), 256, 0, stream>>>(x_bf, qkvw_bf + 2 * E_ * E_, qkv_b, vt_bf);
    // grid: x = bh (XCD affinity), y = qtile (128 q-rows per block)
    flash_attn<<<dim3(32, 16), 256, 0, stream>>>(qk_bf, vt_bf, mask, attn_bf);
    proj_gemm<<<dim3(32, 16), 256, 0, stream>>>(attn_bf, projw_bf, proj_b, out);
}